// Round 10
// baseline (627.427 us; speedup 1.0000x reference)
//
#include <hip/hip_runtime.h>
#include <hip/hip_bf16.h>

// Problem dims
#define V_    10000
#define ENC_  2048
#define D_    512
#define B_    128
#define L_    64
#define T_    63          // L-1 timesteps
#define M_    (B_ * L_ - B_)   // 8064 rows (b*63 + t)
#define G_    (3 * D_)    // 1536 gate width
#define LOGITS_SZ ((long)M_ * V_)   // 80,640,000
#define NSCAN 64          // 2 batch-halves x 32 d-strips
#define NWORK 158         // 2 halves x 79 n-bands

typedef __bf16 bf16x8_t __attribute__((ext_vector_type(8)));
typedef float  f32x4_t  __attribute__((ext_vector_type(4)));
typedef short  s16x8_t  __attribute__((ext_vector_type(8)));
typedef unsigned long long ull_t;

typedef __attribute__((address_space(3))) char*       lds_cptr_t;
typedef const __attribute__((address_space(1))) char* glb_cptr_t;

__device__ __forceinline__ void gload_lds16(const void* g, void* l) {
  __builtin_amdgcn_global_load_lds((glb_cptr_t)g, (lds_cptr_t)l, 16, 0, 0);
}
__device__ __forceinline__ float bf2f(short s) {
  return __uint_as_float(((unsigned)(unsigned short)s) << 16);
}
__device__ __forceinline__ short f2bf(float f) {
  __hip_bfloat16 h = __float2bfloat16(f);  // RNE
  return *reinterpret_cast<short*>(&h);
}
__device__ __forceinline__ s16x8_t cvt8(const float* p) {
  f32x4_t lo = *reinterpret_cast<const f32x4_t*>(p);
  f32x4_t hi = *reinterpret_cast<const f32x4_t*>(p + 4);
  s16x8_t r;
#pragma unroll
  for (int e = 0; e < 4; e++) { r[e] = f2bf(lo[e]); r[4 + e] = f2bf(hi[e]); }
  return r;
}
__device__ __forceinline__ float sigmoidf_(float x) {
  return 1.0f / (1.0f + __expf(-x));
}
__device__ __forceinline__ bf16x8_t lds_frag(const short* p) {
  return __builtin_bit_cast(bf16x8_t, *reinterpret_cast<const s16x8_t*>(p));
}

// ---------------- fused f32 -> bf16 converts (5 segments, 1 launch) ----------------
__global__ void GG_cvt5(const float* __restrict__ whh, __hip_bfloat16* __restrict__ dwhh,
                        const float* __restrict__ wih, __hip_bfloat16* __restrict__ dwih,
                        const float* __restrict__ wemb, __hip_bfloat16* __restrict__ dwemb,
                        const float* __restrict__ winit, __hip_bfloat16* __restrict__ dwinit,
                        const float* __restrict__ gf, __hip_bfloat16* __restrict__ dgf) {
  const int i = blockIdx.x * blockDim.x + threadIdx.x;
  const float* s; __hip_bfloat16* d; int off;
  if (i < 98304)        { s = whh;   d = dwhh;   off = i; }
  else if (i < 196608)  { s = wih;   d = dwih;   off = i - 98304; }
  else if (i < 836608)  { s = wemb;  d = dwemb;  off = i - 196608; }
  else if (i < 967680)  { s = winit; d = dwinit; off = i - 836608; }
  else                  { s = gf;    d = dgf;    off = i - 967680; }
  s16x8_t v = cvt8(s + (long)off * 8);
  *reinterpret_cast<s16x8_t*>(d + (long)off * 8) = v;
}

__global__ void GG_cvt_kernel(const float* __restrict__ src,
                              __hip_bfloat16* __restrict__ dst, int n8) {
  int i = blockIdx.x * blockDim.x + threadIdx.x;
  if (i < n8) {
    s16x8_t v = cvt8(src + (long)i * 8);
    *reinterpret_cast<s16x8_t*>(dst + (long)i * 8) = v;
  }
}

// ---------------- h0 GEMM: hfull[b][0][:] = tanh(gf @ W_init^T + b_init) ----------------
__global__ __launch_bounds__(256) void GG_gemm_h0(
    const __hip_bfloat16* __restrict__ gfB,     // [128][2048] bf16
    const __hip_bfloat16* __restrict__ WinitB,  // [512][2048] bf16
    const float* __restrict__ binit,            // [512] f32
    __hip_bfloat16* __restrict__ hfull) {       // [B][64][512]
  __shared__ short sA[128 * 64];
  __shared__ short sB[128 * 64];
  const int lane = threadIdx.x & 63;
  const int wave = threadIdx.x >> 6;
  const int n0 = blockIdx.x * 128;
  const int srow = lane >> 3;
  const int scol = (lane & 7) * 8;

  f32x4_t acc[4][4] = {};

  const __hip_bfloat16* aptr[4];
  const __hip_bfloat16* bptr[4];
#pragma unroll
  for (int i = 0; i < 4; i++) {
    const int r = (wave * 4 + i) * 8 + srow;
    aptr[i] = gfB + (long)r * ENC_ + scol;
    bptr[i] = WinitB + (long)(n0 + r) * ENC_ + scol;
  }

  const int wm = (wave >> 1) * 64;
  const int wn = (wave & 1) * 64;
  const int fr = lane & 15;
  const int fk = (lane >> 4) * 8;

  for (int kt = 0; kt < 32; kt++) {
    __syncthreads();
#pragma unroll
    for (int i = 0; i < 4; i++) {
      const int chunk = wave * 4 + i;
      gload_lds16(aptr[i] + kt * 64, sA + chunk * 512);
      gload_lds16(bptr[i] + kt * 64, sB + chunk * 512);
    }
    __syncthreads();
#pragma unroll
    for (int kk = 0; kk < 2; kk++) {
      bf16x8_t a[4], b[4];
#pragma unroll
      for (int i = 0; i < 4; i++) {
        a[i] = lds_frag(sA + (wm + i * 16 + fr) * 64 + kk * 32 + fk);
        b[i] = lds_frag(sB + (wn + i * 16 + fr) * 64 + kk * 32 + fk);
      }
#pragma unroll
      for (int i = 0; i < 4; i++)
#pragma unroll
        for (int j = 0; j < 4; j++)
          acc[i][j] = __builtin_amdgcn_mfma_f32_16x16x32_bf16(a[i], b[j], acc[i][j], 0, 0, 0);
    }
  }

  const int fq = lane >> 4;
#pragma unroll
  for (int j = 0; j < 4; j++) {
    const int n = n0 + wn + j * 16 + fr;
    const float bv = binit[n];
#pragma unroll
    for (int i = 0; i < 4; i++)
#pragma unroll
      for (int rr = 0; rr < 4; rr++) {
        const int m = wm + i * 16 + fq * 4 + rr;
        hfull[(long)m * 64 * 512 + n] = __float2bfloat16(tanhf(acc[i][j][rr] + bv));
      }
  }
}

// ---------------- gi GEMM: gi = gather(W_embed,cap) @ W_ih^T + b_ih ----------------
__global__ __launch_bounds__(256) void GG_gemm_gi(
    const __hip_bfloat16* __restrict__ WembB,  // [V][512] bf16
    const int* __restrict__ cap,               // [B][L] int32
    const __hip_bfloat16* __restrict__ WihB,   // [G][512] bf16
    const float* __restrict__ bias,            // [G] f32
    __hip_bfloat16* __restrict__ C) {          // [M][G]
  __shared__ short sA[128 * 64];
  __shared__ short sB[128 * 64];
  const int lane = threadIdx.x & 63;
  const int wave = threadIdx.x >> 6;
  const int m0 = blockIdx.y * 128;
  const int n0 = blockIdx.x * 128;
  const int srow = lane >> 3;
  const int scol = (lane & 7) * 8;

  f32x4_t acc[4][4] = {};

  const __hip_bfloat16* aptr[4];
  const __hip_bfloat16* bptr[4];
#pragma unroll
  for (int i = 0; i < 4; i++) {
    const int r = (wave * 4 + i) * 8 + srow;
    const int bt = m0 + r;
    const int bb = bt / 63;
    const int tt = bt - bb * 63;
    aptr[i] = WembB + (long)cap[bb * L_ + tt] * 512 + scol;
    bptr[i] = WihB + (long)(n0 + r) * 512 + scol;
  }

  const int wm = (wave >> 1) * 64;
  const int wn = (wave & 1) * 64;
  const int fr = lane & 15;
  const int fk = (lane >> 4) * 8;

  for (int kt = 0; kt < 8; kt++) {
    __syncthreads();
#pragma unroll
    for (int i = 0; i < 4; i++) {
      const int chunk = wave * 4 + i;
      gload_lds16(aptr[i] + kt * 64, sA + chunk * 512);
      gload_lds16(bptr[i] + kt * 64, sB + chunk * 512);
    }
    __syncthreads();
#pragma unroll
    for (int kk = 0; kk < 2; kk++) {
      bf16x8_t a[4], b[4];
#pragma unroll
      for (int i = 0; i < 4; i++) {
        a[i] = lds_frag(sA + (wm + i * 16 + fr) * 64 + kk * 32 + fk);
        b[i] = lds_frag(sB + (wn + i * 16 + fr) * 64 + kk * 32 + fk);
      }
#pragma unroll
      for (int i = 0; i < 4; i++)
#pragma unroll
        for (int j = 0; j < 4; j++)
          acc[i][j] = __builtin_amdgcn_mfma_f32_16x16x32_bf16(a[i], b[j], acc[i][j], 0, 0, 0);
    }
  }

  const int fq = lane >> 4;
#pragma unroll
  for (int j = 0; j < 4; j++) {
    const int n = n0 + wn + j * 16 + fr;
    const float bv = bias[n];
#pragma unroll
    for (int i = 0; i < 4; i++)
#pragma unroll
      for (int rr = 0; rr < 4; rr++) {
        const int m = m0 + wm + i * 16 + fq * 4 + rr;
        C[(long)m * G_ + n] = __float2bfloat16(acc[i][j][rr] + bv);
      }
  }
}

// ---------------- standalone logits GEMM (fallback path) ----------------
template <bool BBF16>
__global__ __launch_bounds__(256) void GG_gemm_logits(
    const __hip_bfloat16* __restrict__ hfull,  // [B][64][512]
    const void* __restrict__ Bsrc,             // W_fc bf16 or f32 [V][512]
    const float* __restrict__ bias,            // [V] f32
    float* __restrict__ C) {                   // [M][V]
  const int flat = blockIdx.x;
  const int xcd = flat & 7;
  const int s = flat >> 3;           // 0..629
  const int col = xcd * 10 + s % 10; // 0..79
  const int row = s / 10;            // 0..62
  if (col >= 79) return;
  const int m0 = row * 128;
  const int n0 = col * 128;

  __shared__ short sA[128 * 64];
  __shared__ short sB[128 * 64];
  const int lane = threadIdx.x & 63;
  const int wave = threadIdx.x >> 6;
  const int srow = lane >> 3;
  const int scol = (lane & 7) * 8;

  f32x4_t acc[4][4] = {};

  const __hip_bfloat16* aptr[4];
  const __hip_bfloat16* bptrB[4];
  const float* bptrF[4];
#pragma unroll
  for (int i = 0; i < 4; i++) {
    const int r = (wave * 4 + i) * 8 + srow;
    const int m = m0 + r;
    const int bb = m / 63;
    const int tt = m - bb * 63;
    aptr[i] = hfull + ((long)bb * 64 + tt + 1) * 512 + scol;
    int nrow = n0 + r;
    nrow = (nrow < V_) ? nrow : (V_ - 1);
    if constexpr (BBF16) bptrB[i] = (const __hip_bfloat16*)Bsrc + (long)nrow * 512 + scol;
    else                 bptrF[i] = (const float*)Bsrc + (long)nrow * 512 + scol;
  }

  const int wm = (wave >> 1) * 64;
  const int wn = (wave & 1) * 64;
  const int fr = lane & 15;
  const int fk = (lane >> 4) * 8;

  for (int kt = 0; kt < 8; kt++) {
    s16x8_t vb[4];
    if constexpr (!BBF16) {
#pragma unroll
      for (int i = 0; i < 4; i++) vb[i] = cvt8(bptrF[i] + kt * 64);
    }
    __syncthreads();
#pragma unroll
    for (int i = 0; i < 4; i++) {
      const int chunk = wave * 4 + i;
      gload_lds16(aptr[i] + kt * 64, sA + chunk * 512);
      if constexpr (BBF16)
        gload_lds16(bptrB[i] + kt * 64, sB + chunk * 512);
      else
        *reinterpret_cast<s16x8_t*>(sB + chunk * 512 + lane * 8) = vb[i];
    }
    __syncthreads();
#pragma unroll
    for (int kk = 0; kk < 2; kk++) {
      bf16x8_t a[4], b[4];
#pragma unroll
      for (int i = 0; i < 4; i++) {
        a[i] = lds_frag(sA + (wm + i * 16 + fr) * 64 + kk * 32 + fk);
        b[i] = lds_frag(sB + (wn + i * 16 + fr) * 64 + kk * 32 + fk);
      }
#pragma unroll
      for (int i = 0; i < 4; i++)
#pragma unroll
        for (int j = 0; j < 4; j++)
          acc[i][j] = __builtin_amdgcn_mfma_f32_16x16x32_bf16(a[i], b[j], acc[i][j], 0, 0, 0);
    }
  }

  const int fq = lane >> 4;
#pragma unroll
  for (int j = 0; j < 4; j++) {
    const int n = n0 + wn + j * 16 + fr;
    if (n >= V_) continue;
    const float bv = bias[n];
#pragma unroll
    for (int i = 0; i < 4; i++)
#pragma unroll
      for (int rr = 0; rr < 4; rr++) {
        const int m = m0 + wm + i * 16 + fq * 4 + rr;
        C[(long)m * V_ + n] = acc[i][j][rr] + bv;
      }
  }
}

// ---------------- merged scan + streaming-logits kernel ----------------
// Blocks [0,64): R9 scan (flags EVERY step, value t+1).
// Blocks [64,64+158): logits workers; worker w: half hh=w&1, n-band nb=w>>1
// (fixed forever -> W_fc band L2-resident). Per t: poll half's flags >= t+1,
// then compute M=64(batch of half) x N=128 x K=512 tile and store f32 C rows
// m = b*63+t. Workers write d_out only after flag(1), by which time every scan
// block has staged its Whh strip (so WhhB scratch in d_out is already dead).
__global__ __launch_bounds__(256) void GG_scan_logits(
    __hip_bfloat16* __restrict__ hfull,       // [B][64][512]
    const __hip_bfloat16* __restrict__ gi,    // [M][G]
    const __hip_bfloat16* __restrict__ WhhB,  // [G][512] bf16
    const float* __restrict__ bhh,            // [G] f32
    int* __restrict__ flagbase,
    const __hip_bfloat16* __restrict__ WfcB,  // [V][512] bf16 (overlap only)
    const float* __restrict__ bfc,            // [V] f32
    float* __restrict__ C) {                  // [M][V]
  __shared__ short smem[48 * 512];  // scan: sW 49152B | worker: sA 8KB + sB 16KB
  const int lane = threadIdx.x & 63;
  const int wave = threadIdx.x >> 6;
  const int fr = lane & 15;
  const int g4 = lane >> 4;

  if (blockIdx.x < NSCAN) {
    // ================= scan role (R9 structure) =================
    short* sW = smem;
    const int strip = blockIdx.x & 31;
    const int half  = blockIdx.x >> 5;
    const int d0 = strip * 16;
    int* myflags = flagbase + half * 32;

    for (int rr = wave; rr < 48; rr += 4) {
      const int grow = (rr >> 4) * 512 + d0 + (rr & 15);
      gload_lds16(WhhB + (long)grow * 512 + (lane ^ (rr & 7)) * 8, sW + rr * 512);
    }

    const int dd = d0 + fr;
    const int bbase = half * 64 + wave * 16 + g4 * 4;
    const float br_ = bhh[dd], bz_ = bhh[512 + dd], bn_ = bhh[1024 + dd];
    const short* gis = (const short*)gi;

    const int arow = half * 64 + wave * 16 + fr;
    const ull_t abase0 =
        (ull_t)hfull + ((ull_t)arow * 64 * 512 + (unsigned)(g4 * 8)) * 2ull;

    ull_t sbase[4];
    const short* gp0[4];
#pragma unroll
    for (int rr = 0; rr < 4; rr++) {
      sbase[rr] = (ull_t)hfull +
                  ((ull_t)(bbase + rr) * 64 * 512 + (unsigned)dd) * 2ull;
      gp0[rr] = gis + (long)(bbase + rr) * T_ * G_ + dd;
    }

    unsigned cr[4], cz[4], cn[4];
    float hp[4];
#pragma unroll
    for (int rr = 0; rr < 4; rr++) {
      cr[rr] = (unsigned short)gp0[rr][0];
      cz[rr] = (unsigned short)gp0[rr][512];
      cn[rr] = (unsigned short)gp0[rr][1024];
      hp[rr] = bf2f(*(const short*)&hfull[((long)(bbase + rr) * 64) * 512 + dd]);
    }

    asm volatile("s_waitcnt vmcnt(0)" ::: "memory");
    __syncthreads();  // sW fully staged

    for (int t = 0; t < T_; t++) {
      if (t > 0) {
        while (true) {
          const int v = __hip_atomic_load(&myflags[lane & 31], __ATOMIC_RELAXED,
                                          __HIP_MEMORY_SCOPE_SYSTEM);
          if (__all(v >= t)) break;
          __builtin_amdgcn_s_sleep(1);
        }
      }

      const ull_t ab = abase0 + (ull_t)t * 1024ull;
      f32x4_t a[16];
#define ALOAD(IDX, OFF)                                                        \
      asm volatile("global_load_dwordx4 %0, %1, off offset:" #OFF " sc0 sc1"   \
                   : "=v"(a[IDX]) : "v"(ab));
      ALOAD(0, 0)    ALOAD(1, 64)   ALOAD(2, 128)  ALOAD(3, 192)
      ALOAD(4, 256)  ALOAD(5, 320)  ALOAD(6, 384)  ALOAD(7, 448)
      ALOAD(8, 512)  ALOAD(9, 576)  ALOAD(10, 640) ALOAD(11, 704)
      ALOAD(12, 768) ALOAD(13, 832) ALOAD(14, 896) ALOAD(15, 960)
#undef ALOAD

      const int tp = (t < T_ - 1) ? (t + 1) : (T_ - 1);
      unsigned nr[4], nz[4], nn[4];
#pragma unroll
      for (int rr = 0; rr < 4; rr++) {
        const short* gp = gp0[rr] + (long)tp * G_;
        asm volatile("global_load_ushort %0, %1, off"             : "=v"(nr[rr]) : "v"(gp));
        asm volatile("global_load_ushort %0, %1, off offset:1024" : "=v"(nz[rr]) : "v"(gp));
        asm volatile("global_load_ushort %0, %1, off offset:2048" : "=v"(nn[rr]) : "v"(gp));
      }

      asm volatile("s_waitcnt vmcnt(12)" ::: "memory");
      __builtin_amdgcn_sched_barrier(0);

      f32x4_t acc[3] = {};
#pragma unroll
      for (int kt = 0; kt < 16; kt++) {
        const bf16x8_t afr = __builtin_bit_cast(bf16x8_t, a[kt]);
        const int gsw = ((kt * 4 + g4) ^ (fr & 7)) * 8;
        bf16x8_t bfr[3];
#pragma unroll
        for (int j = 0; j < 3; j++) bfr[j] = lds_frag(sW + (j * 16 + fr) * 512 + gsw);
#pragma unroll
        for (int j = 0; j < 3; j++)
          acc[j] = __builtin_amdgcn_mfma_f32_16x16x32_bf16(afr, bfr[j], acc[j], 0, 0, 0);
      }

#pragma unroll
      for (int rr = 0; rr < 4; rr++) {
        const float rg = sigmoidf_(bf2f((short)cr[rr]) + acc[0][rr] + br_);
        const float zg = sigmoidf_(bf2f((short)cz[rr]) + acc[1][rr] + bz_);
        const float ng = tanhf(bf2f((short)cn[rr]) + rg * (acc[2][rr] + bn_));
        const short hnb = f2bf((1.f - zg) * ng + zg * hp[rr]);
        hp[rr] = bf2f(hnb);
        const ull_t saddr = sbase[rr] + (ull_t)(t + 1) * 1024ull;
        const unsigned int val = (unsigned short)hnb;
        asm volatile("global_store_short %0, %1, off sc0 sc1"
                     :: "v"(saddr), "v"(val) : "memory");
      }

      asm volatile("s_waitcnt vmcnt(0)" ::: "memory");
      __builtin_amdgcn_sched_barrier(0);
#pragma unroll
      for (int rr = 0; rr < 4; rr++) { cr[rr] = nr[rr]; cz[rr] = nz[rr]; cn[rr] = nn[rr]; }

      __syncthreads();  // whole block's stores drained
      if (threadIdx.x == 0)
        __hip_atomic_store(&myflags[strip], t + 1, __ATOMIC_RELAXED,
                           __HIP_MEMORY_SCOPE_SYSTEM);
    }
  } else {
    // ================= logits worker role =================
    const int w = blockIdx.x - NSCAN;   // 0..157
    const int hh = w & 1;
    const int nb = w >> 1;              // 0..78
    const int n0 = nb * 128;
    short* sA = smem;                   // [64][64]
    short* sB = smem + 64 * 64;         // [128][64]
    int* myflags = flagbase + hh * 32;

    const int srow = lane >> 3;
    const int scol = (lane & 7) * 8;
    const int wm = (wave >> 1) * 32;
    const int wn = (wave & 1) * 64;
    const int fk = g4 * 8;
    const int fq = g4;

    // B row pointers (fixed across t)
    const __hip_bfloat16* bptr[4];
#pragma unroll
    for (int i = 0; i < 4; i++) {
      int nrow = n0 + (wave * 4 + i) * 8 + srow;
      nrow = (nrow < V_) ? nrow : (V_ - 1);
      bptr[i] = WfcB + (long)nrow * 512 + scol;
    }
    // A row base (without t): batch b = hh*64 + chunk*8+srow, chunk = wave*2+i
    const __hip_bfloat16* abase[2];
#pragma unroll
    for (int i = 0; i < 2; i++) {
      const int b = hh * 64 + (wave * 2 + i) * 8 + srow;
      abase[i] = hfull + (long)b * 64 * 512 + scol;
    }
    // bias (fixed across t)
    float bv[4];
#pragma unroll
    for (int j = 0; j < 4; j++) {
      const int n = n0 + wn + j * 16 + fr;
      bv[j] = bfc[(n < V_) ? n : (V_ - 1)];
    }

    for (int t = 0; t < T_; t++) {
      // poll: half hh's h[t+1] ready
      while (true) {
        const int v = __hip_atomic_load(&myflags[lane & 31], __ATOMIC_RELAXED,
                                        __HIP_MEMORY_SCOPE_SYSTEM);
        if (__all(v >= t + 1)) break;
        __builtin_amdgcn_s_sleep(32);
      }

      f32x4_t acc[2][4] = {};
      for (int kt = 0; kt < 8; kt++) {
        __syncthreads();  // prev iter's LDS reads done
#pragma unroll
        for (int i = 0; i < 2; i++) {
          const int chunk = wave * 2 + i;
          gload_lds16(abase[i] + (long)(t + 1) * 512 + kt * 64, sA + chunk * 512);
        }
#pragma unroll
        for (int i = 0; i < 4; i++) {
          const int chunk = wave * 4 + i;
          gload_lds16(bptr[i] + kt * 64, sB + chunk * 512);
        }
        __syncthreads();  // tiles staged
#pragma unroll
        for (int kk = 0; kk < 2; kk++) {
          bf16x8_t a[2], b[4];
#pragma unroll
          for (int i = 0; i < 2; i++)
            a[i] = lds_frag(sA + (wm + i * 16 + fr) * 64 + kk * 32 + fk);
#pragma unroll
          for (int j = 0; j < 4; j++)
            b[j] = lds_frag(sB + (wn + j * 16 + fr) * 64 + kk * 32 + fk);
#pragma unroll
          for (int i = 0; i < 2; i++)
#pragma unroll
            for (int j = 0; j < 4; j++)
              acc[i][j] = __builtin_amdgcn_mfma_f32_16x16x32_bf16(a[i], b[j], acc[i][j], 0, 0, 0);
        }
      }
      __syncthreads();  // LDS reads done before next t re-stages

      // epilogue: C rows m = b*63 + t
#pragma unroll
      for (int j = 0; j < 4; j++) {
        const int n = n0 + wn + j * 16 + fr;
        if (n >= V_) continue;
#pragma unroll
        for (int i = 0; i < 2; i++)
#pragma unroll
          for (int rr = 0; rr < 4; rr++) {
            const int b = hh * 64 + wm + i * 16 + fq * 4 + rr;
            C[((long)b * 63 + t) * V_ + n] = acc[i][j][rr] + bv[j];
          }
      }
    }
  }
}

// ---------------- tail: out[LOGITS_SZ + b] = f32(len[b] - 1) ----------------
__global__ void GG_tail_kernel(const int* __restrict__ lens, float* __restrict__ out) {
  const int b = threadIdx.x;
  if (b < B_) out[LOGITS_SZ + b] = (float)(lens[b] - 1);
}

extern "C" void kernel_launch(void* const* d_in, const int* in_sizes, int n_in,
                              void* d_out, int out_size, void* d_ws, size_t ws_size,
                              hipStream_t stream) {
  const float* gf      = (const float*)d_in[0];
  const int*   cap     = (const int*)d_in[1];
  const int*   lens    = (const int*)d_in[2];
  const float* W_embed = (const float*)d_in[3];
  const float* W_init  = (const float*)d_in[4];
  const float* b_init  = (const float*)d_in[5];
  const float* W_ih    = (const float*)d_in[6];
  const float* W_hh    = (const float*)d_in[7];
  const float* b_ih    = (const float*)d_in[8];
  const float* b_hh    = (const float*)d_in[9];
  const float* W_fc    = (const float*)d_in[10];
  const float* b_fc    = (const float*)d_in[11];
  float* out = (float*)d_out;

  // d_out scratch (dead before workers/logits write d_out):
  char* ob = (char*)d_out;
  __hip_bfloat16* WhhB   = (__hip_bfloat16*)(ob + 25165824);  // 1.5 MB
  __hip_bfloat16* WihB   = (__hip_bfloat16*)(ob + 27262976);  // 1.5 MB
  __hip_bfloat16* WembB  = (__hip_bfloat16*)(ob + 29360128);  // 10 MB
  __hip_bfloat16* WinitB = (__hip_bfloat16*)(ob + 40894464);  // 2 MB
  __hip_bfloat16* gfB    = (__hip_bfloat16*)(ob + 43253760);  // 0.5 MB

  // ws layouts
  char* ws = (char*)d_ws;
  __hip_bfloat16* hfull = (__hip_bfloat16*)ws;  // 8,388,608 B
  const bool overlap = ws_size >= (size_t)43401728;
  const bool bigws   = ws_size >= (size_t)18628864;
  int* flags;
  __hip_bfloat16* WfcB = nullptr;
  __hip_bfloat16* giP;
  if (overlap) {
    flags = (int*)(ws + 8388608);                       // 512 B
    WfcB  = (__hip_bfloat16*)(ws + 8389120);            // 10,240,000 B
    giP   = (__hip_bfloat16*)(ws + 18629120);           // 24,772,608 B -> 43,401,728
  } else {
    giP = (__hip_bfloat16*)d_out;                       // R9 fallback: gi in d_out
    if (bigws) { WfcB = (__hip_bfloat16*)(ws + 8388608); flags = (int*)(ws + 18628608); }
    else       { flags = (int*)(ws + 8388608); }
  }

  // 0. reset barrier flags
  hipMemsetAsync(flags, 0, 256, stream);

  // 1. weight/input converts to bf16
  GG_cvt5<<<dim3(3908), 256, 0, stream>>>(W_hh, WhhB, W_ih, WihB, W_embed, WembB,
                                          W_init, WinitB, gf, gfB);
  if (overlap || bigws)
    GG_cvt_kernel<<<dim3((V_ * D_ / 8 + 255) / 256), 256, 0, stream>>>(W_fc, WfcB, V_ * D_ / 8);

  // 2. h0 -> hfull slot 0
  GG_gemm_h0<<<dim3(4), 256, 0, stream>>>(gfB, WinitB, b_init, hfull);

  // 3. gi = gather(W_embed, cap) @ W_ih^T + b_ih
  GG_gemm_gi<<<dim3(G_ / 128, M_ / 128), 256, 0, stream>>>(WembB, cap, WihB, b_ih, giP);

  // 4. scan (+ streaming logits when overlap)
  const int nblk = overlap ? (NSCAN + NWORK) : NSCAN;
  GG_scan_logits<<<dim3(nblk), 256, 0, stream>>>(hfull, giP, WhhB, b_hh, flags,
                                                 WfcB, b_fc, out);

  // 5. standalone logits (fallback only)
  if (!overlap) {
    if (bigws)
      GG_gemm_logits<true><<<dim3(5040), 256, 0, stream>>>(hfull, WfcB, b_fc, out);
    else
      GG_gemm_logits<false><<<dim3(5040), 256, 0, stream>>>(hfull, W_fc, b_fc, out);
  }

  // 6. second output
  GG_tail_kernel<<<dim3(1), 128, 0, stream>>>(lens, out);
}